// Round 18
// baseline (287.780 us; speedup 1.0000x reference)
//
#include <hip/hip_runtime.h>

constexpr int BB = 2, HH = 16, LL = 2048, DD = 128;
constexpr int QB = 64, KB = 32, NKT = LL / KB;   // 64 k-tiles
constexpr float SCALE = 0.08838834764831845f;    // 1/sqrt(128)

typedef __attribute__((ext_vector_type(8))) short bf16x8;
typedef __attribute__((ext_vector_type(8))) unsigned short u16x8;
typedef __attribute__((ext_vector_type(4))) float f32x4;
typedef __attribute__((ext_vector_type(4))) int i32x4;

static __device__ __forceinline__ unsigned short f2bf(float f) {
  unsigned int u = __builtin_bit_cast(unsigned int, f);
  u += 0x7fffu + ((u >> 16) & 1u);   // RNE
  return (unsigned short)(u >> 16);
}
static __device__ __forceinline__ float bf2f(unsigned short h) {
  return __builtin_bit_cast(float, (unsigned int)h << 16);
}

#define GLD16(gsrc, ldst) __builtin_amdgcn_global_load_lds( \
    (const __attribute__((address_space(1))) void*)(gsrc), \
    (__attribute__((address_space(3))) void*)(ldst), 16, 0, 0)

// ---------------- prep ----------------
//   kbT tile [16 dslots][32 keys][8 d] (bf16)
//   vtT tile [4 kc][128 d][8 keys]     (bf16)
//   biasT[b][qt][kt][wid][lane][8]     (bf16) lane-packed: wave's per-iter bias
__global__ __launch_bounds__(256)
void prep_kernel(const float* __restrict__ k, const float* __restrict__ v,
                 const int* __restrict__ mask, const float* __restrict__ probs,
                 const float* __restrict__ alphap,
                 unsigned short* __restrict__ kbT, unsigned short* __restrict__ vtT,
                 unsigned short* __restrict__ biasW)
{
  __shared__ unsigned short sT[128 * 40];   // V^T tile, 80 B rows
  const int bid = blockIdx.x;
  const int bh = bid >> 6, kt = bid & 63;
  const int t = threadIdx.x;
  const float alpha = alphap[0];
  const size_t tileBase = (size_t)bid * 4096;   // bid == bh*64 + kt
  const float* kg = k + ((size_t)bh * LL + kt * 32) * DD;
  const float* vg = v + ((size_t)bh * LL + kt * 32) * DD;

  // K -> 16B-block-transposed tile
  #pragma unroll
  for (int s = t; s < 512; s += 256) {
    int dsl = s >> 5, key = s & 31;
    const float* src = kg + key * DD + dsl * 8;
    float4 a = *(const float4*)src;
    float4 c = *(const float4*)(src + 4);
    u16x8 w;
    w[0] = f2bf(a.x); w[1] = f2bf(a.y); w[2] = f2bf(a.z); w[3] = f2bf(a.w);
    w[4] = f2bf(c.x); w[5] = f2bf(c.y); w[6] = f2bf(c.z); w[7] = f2bf(c.w);
    *(u16x8*)(kbT + tileBase + (size_t)s * 8) = w;
  }
  // V -> sT (transpose)
  #pragma unroll
  for (int i = 0; i < 4; ++i) {
    int idx = i * 256 + t;
    int key = idx >> 5, d4 = (idx & 31) * 4;
    float4 x = ((const float4*)vg)[idx];
    sT[(d4 + 0) * 40 + key] = f2bf(x.x);
    sT[(d4 + 1) * 40 + key] = f2bf(x.y);
    sT[(d4 + 2) * 40 + key] = f2bf(x.z);
    sT[(d4 + 3) * 40 + key] = f2bf(x.w);
  }
  // biasT: 2 tiles per block (4096 tiles total, 2048 u16 each)
  #pragma unroll
  for (int it = 0; it < 2; ++it) {
    int tileIdx = bid * 2 + it;            // 0..4095
    int b = tileIdx >> 11;
    int rem = tileIdx & 2047;
    int tq = rem >> 6;                     // qt 0..31
    int tk = rem & 63;                     // kt 0..63
    int row = ((t >> 6) << 4) + (t & 15);  // widx*16 + l15
    int kc = ((t >> 4) & 3) * 4;           // l4*4
    const float* pr = probs + (size_t)b * LL * LL + (size_t)(tq * 64 + row) * LL + tk * 32;
    const int* mr = mask + (size_t)b * LL * LL + (size_t)(tq * 64 + row) * LL + tk * 32;
    float4 f0 = *(const float4*)(pr + kc);
    float4 f1 = *(const float4*)(pr + kc + 16);
    int4 m0 = *(const int4*)(mr + kc);
    int4 m1 = *(const int4*)(mr + kc + 16);
    u16x8 o;
    o[0] = f2bf(m0.x ? f0.x * alpha : -1e30f);
    o[1] = f2bf(m0.y ? f0.y * alpha : -1e30f);
    o[2] = f2bf(m0.z ? f0.z * alpha : -1e30f);
    o[3] = f2bf(m0.w ? f0.w * alpha : -1e30f);
    o[4] = f2bf(m1.x ? f1.x * alpha : -1e30f);
    o[5] = f2bf(m1.y ? f1.y * alpha : -1e30f);
    o[6] = f2bf(m1.z ? f1.z * alpha : -1e30f);
    o[7] = f2bf(m1.w ? f1.w * alpha : -1e30f);
    *(u16x8*)(biasW + (size_t)tileIdx * 2048 + t * 8) = o;
  }
  __syncthreads();
  // sT -> vtT tile [kc][d][8]
  #pragma unroll
  for (int s = t; s < 512; s += 256) {
    int kc = s >> 7, d = s & 127;
    u16x8 w = *(const u16x8*)&sT[d * 40 + kc * 8];
    *(u16x8*)(vtT + tileBase + (size_t)s * 8) = w;
  }
}

// ---------------- pass A: rowsums -> invW ----------------
// 16 KB LDS -> HW cap 10 WGs/CU; request 8 (VGPR <= 64) for full occupancy.
__global__ __launch_bounds__(256, 8)
void passA_kernel(const float* __restrict__ q, const unsigned short* __restrict__ kbT,
                  const unsigned short* __restrict__ biasW, float* __restrict__ invW)
{
  __shared__ unsigned short sK[2][4096];

  const int tid = threadIdx.x;
  const int lane = tid & 63;
  const int wid = tid >> 6;
  const int l15 = lane & 15;
  const int l4 = lane >> 4;

  const int bid = blockIdx.x;
  const int work = ((bid & 7) << 7) | (bid >> 3);
  const int bh = work >> 5;
  const int qt = work & 31;
  const int b = bh >> 4;
  const int q0 = qt * QB;
  const int row16 = wid << 4;

  const unsigned short* kbh = kbT + (size_t)bh * 64 * 4096;
  const unsigned short* bg = biasW + ((size_t)(b * 32 + qt) * 64) * 2048 + (wid << 9) + (lane << 3);

  bf16x8 qf0, qf1, qf2, qf3;
  {
    const float* qs = q + (size_t)(bh * LL + q0 + row16 + l15) * DD + l4 * 8;
    #define LQ(FR, KC) { \
      float4 a = *(const float4*)(qs + (KC) * 32); \
      float4 c = *(const float4*)(qs + (KC) * 32 + 4); \
      FR[0]=(short)f2bf(a.x); FR[1]=(short)f2bf(a.y); FR[2]=(short)f2bf(a.z); FR[3]=(short)f2bf(a.w); \
      FR[4]=(short)f2bf(c.x); FR[5]=(short)f2bf(c.y); FR[6]=(short)f2bf(c.z); FR[7]=(short)f2bf(c.w); }
    LQ(qf0, 0) LQ(qf1, 1) LQ(qf2, 2) LQ(qf3, 3)
    #undef LQ
  }

  #define DMA_K(BUF, KT) do { \
    GLD16(kbh + (size_t)(KT) * 4096 + tid * 8,         &sK[BUF][wid << 9]); \
    GLD16(kbh + (size_t)(KT) * 4096 + (256 + tid) * 8, &sK[BUF][2048 + (wid << 9)]); } while (0)

  #define QKS(KC, QF) { \
    bf16x8 k0 = *(const bf16x8*)&sK[cur][(((KC) * 4 + l4) * 32 + l15) * 8]; \
    a0 = __builtin_amdgcn_mfma_f32_16x16x32_bf16(k0, QF, a0, 0, 0, 0); \
    bf16x8 k1 = *(const bf16x8*)&sK[cur][(((KC) * 4 + l4) * 32 + 16 + l15) * 8]; \
    a1 = __builtin_amdgcn_mfma_f32_16x16x32_bf16(k1, QF, a1, 0, 0, 0); }

  DMA_K(0, 0);
  u16x8 cnb = *(const u16x8*)(bg);
  float sum = 0.f;
  for (int kt = 0; kt < NKT; ++kt) {
    const int cur = kt & 1;
    __syncthreads();
    if (kt + 1 < NKT) DMA_K(cur ^ 1, kt + 1);
    u16x8 bt = cnb;
    if (kt + 1 < NKT) cnb = *(const u16x8*)(bg + (size_t)(kt + 1) * 2048);
    f32x4 a0 = {0.f,0.f,0.f,0.f}, a1 = {0.f,0.f,0.f,0.f};
    QKS(0, qf0) QKS(1, qf1) QKS(2, qf2) QKS(3, qf3)
    sum += __expf(a0[0] * SCALE + bf2f(bt[0]));
    sum += __expf(a0[1] * SCALE + bf2f(bt[1]));
    sum += __expf(a0[2] * SCALE + bf2f(bt[2]));
    sum += __expf(a0[3] * SCALE + bf2f(bt[3]));
    sum += __expf(a1[0] * SCALE + bf2f(bt[4]));
    sum += __expf(a1[1] * SCALE + bf2f(bt[5]));
    sum += __expf(a1[2] * SCALE + bf2f(bt[6]));
    sum += __expf(a1[3] * SCALE + bf2f(bt[7]));
  }
  sum += __shfl_xor(sum, 16, 64);
  sum += __shfl_xor(sum, 32, 64);
  if (l4 == 0)
    invW[(size_t)bh * LL + q0 + row16 + l15] = 1.0f / sum;
  #undef DMA_K
  #undef QKS
}

// ---------------- pass B: attn_p + O ----------------
// 32 KB LDS -> HW cap 5 WGs/CU; request 5 (VGPR <= ~102).
__global__ __launch_bounds__(256, 5)
void passB_kernel(const float* __restrict__ q, const unsigned short* __restrict__ kbT,
                  const unsigned short* __restrict__ vtT, const unsigned short* __restrict__ biasW,
                  const float* __restrict__ invW,
                  float* __restrict__ outA, float* __restrict__ outP)
{
  __shared__ unsigned short sK[2][4096];
  __shared__ unsigned short sVt[2][4096];

  const int tid = threadIdx.x;
  const int lane = tid & 63;
  const int wid = tid >> 6;
  const int l15 = lane & 15;
  const int l4 = lane >> 4;

  const int bid = blockIdx.x;
  const int work = ((bid & 7) << 7) | (bid >> 3);
  const int bh = work >> 5;
  const int qt = work & 31;
  const int b = bh >> 4;
  const int q0 = qt * QB;
  const int row16 = wid << 4;

  const unsigned short* kbh = kbT + (size_t)bh * 64 * 4096;
  const unsigned short* vbh = vtT + (size_t)bh * 64 * 4096;
  const unsigned short* bg = biasW + ((size_t)(b * 32 + qt) * 64) * 2048 + (wid << 9) + (lane << 3);
  float* oA = outA + (size_t)(bh * LL + q0) * DD;
  float* oPr = outP + (size_t)bh * LL * LL + (size_t)(q0 + row16 + l15) * LL;

  const float inv = invW[(size_t)bh * LL + q0 + row16 + l15];

  bf16x8 qf0, qf1, qf2, qf3;
  {
    const float* qs = q + (size_t)(bh * LL + q0 + row16 + l15) * DD + l4 * 8;
    #define LQ(FR, KC) { \
      float4 a = *(const float4*)(qs + (KC) * 32); \
      float4 c = *(const float4*)(qs + (KC) * 32 + 4); \
      FR[0]=(short)f2bf(a.x); FR[1]=(short)f2bf(a.y); FR[2]=(short)f2bf(a.z); FR[3]=(short)f2bf(a.w); \
      FR[4]=(short)f2bf(c.x); FR[5]=(short)f2bf(c.y); FR[6]=(short)f2bf(c.z); FR[7]=(short)f2bf(c.w); }
    LQ(qf0, 0) LQ(qf1, 1) LQ(qf2, 2) LQ(qf3, 3)
    #undef LQ
  }

  #define DMA_K(BUF, KT) do { \
    GLD16(kbh + (size_t)(KT) * 4096 + tid * 8,         &sK[BUF][wid << 9]); \
    GLD16(kbh + (size_t)(KT) * 4096 + (256 + tid) * 8, &sK[BUF][2048 + (wid << 9)]); } while (0)
  #define DMA_V(BUF, KT) do { \
    GLD16(vbh + (size_t)(KT) * 4096 + tid * 8,         &sVt[BUF][wid << 9]); \
    GLD16(vbh + (size_t)(KT) * 4096 + (256 + tid) * 8, &sVt[BUF][2048 + (wid << 9)]); } while (0)

  #define QKS(KC, QF) { \
    bf16x8 k0 = *(const bf16x8*)&sK[cur][(((KC) * 4 + l4) * 32 + l15) * 8]; \
    a0 = __builtin_amdgcn_mfma_f32_16x16x32_bf16(k0, QF, a0, 0, 0, 0); \
    bf16x8 k1 = *(const bf16x8*)&sK[cur][(((KC) * 4 + l4) * 32 + 16 + l15) * 8]; \
    a1 = __builtin_amdgcn_mfma_f32_16x16x32_bf16(k1, QF, a1, 0, 0, 0); }

  const int srcA = l15 + (((l4 << 1) + 0) & 3) * 16;
  const int srcB = l15 + (((l4 << 1) + 1) & 3) * 16;
  const bool hiTile = (l4 >= 2);

  f32x4 oacc[8];
  #pragma unroll
  for (int dt = 0; dt < 8; ++dt) oacc[dt] = (f32x4){0.f,0.f,0.f,0.f};

  u16x8 cnb;

  #define BBODY(KT) do { \
    const int cur = (KT) & 1; \
    u16x8 bt = cnb; \
    if ((KT) + 1 < NKT) cnb = *(const u16x8*)(bg + (size_t)((KT) + 1) * 2048); \
    f32x4 a0 = {0.f,0.f,0.f,0.f}, a1 = {0.f,0.f,0.f,0.f}; \
    QKS(0, qf0) QKS(1, qf1) QKS(2, qf2) QKS(3, qf3) \
    f32x4 p0, p1; \
    p0[0] = __expf(a0[0] * SCALE + bf2f(bt[0])) * inv; \
    p0[1] = __expf(a0[1] * SCALE + bf2f(bt[1])) * inv; \
    p0[2] = __expf(a0[2] * SCALE + bf2f(bt[2])) * inv; \
    p0[3] = __expf(a0[3] * SCALE + bf2f(bt[3])) * inv; \
    p1[0] = __expf(a1[0] * SCALE + bf2f(bt[4])) * inv; \
    p1[1] = __expf(a1[1] * SCALE + bf2f(bt[5])) * inv; \
    p1[2] = __expf(a1[2] * SCALE + bf2f(bt[6])) * inv; \
    p1[3] = __expf(a1[3] * SCALE + bf2f(bt[7])) * inv; \
    __builtin_nontemporal_store(p0, (f32x4*)(oPr + (KT) * 32 + (l4 << 2))); \
    __builtin_nontemporal_store(p1, (f32x4*)(oPr + (KT) * 32 + 16 + (l4 << 2))); \
    unsigned d00, d01, d10, d11; \
    asm("v_cvt_pk_bf16_f32 %0, %1, %2" : "=v"(d00) : "v"(p0[0]), "v"(p0[1])); \
    asm("v_cvt_pk_bf16_f32 %0, %1, %2" : "=v"(d01) : "v"(p0[2]), "v"(p0[3])); \
    asm("v_cvt_pk_bf16_f32 %0, %1, %2" : "=v"(d10) : "v"(p1[0]), "v"(p1[1])); \
    asm("v_cvt_pk_bf16_f32 %0, %1, %2" : "=v"(d11) : "v"(p1[2]), "v"(p1[3])); \
    int a00 = __shfl((int)d00, srcA, 64); \
    int a01 = __shfl((int)d01, srcA, 64); \
    int a02 = __shfl((int)d00, srcB, 64); \
    int a03 = __shfl((int)d01, srcB, 64); \
    int b00 = __shfl((int)d10, srcA, 64); \
    int b01 = __shfl((int)d11, srcA, 64); \
    int b02 = __shfl((int)d10, srcB, 64); \
    int b03 = __shfl((int)d11, srcB, 64); \
    i32x4 fw; \
    fw[0] = hiTile ? b00 : a00; \
    fw[1] = hiTile ? b01 : a01; \
    fw[2] = hiTile ? b02 : a02; \
    fw[3] = hiTile ? b03 : a03; \
    bf16x8 aP = __builtin_bit_cast(bf16x8, fw); \
    _Pragma("unroll") \
    for (int dt = 0; dt < 8; ++dt) { \
      bf16x8 bV = *(const bf16x8*)&sVt[cur][(l4 * 128 + dt * 16 + l15) * 8]; \
      oacc[dt] = __builtin_amdgcn_mfma_f32_16x16x32_bf16(aP, bV, oacc[dt], 0, 0, 0); \
    } \
  } while (0)

  // prologue: bias first, then DMA (stores later stay the newest-2 ops)
  cnb = *(const u16x8*)(bg);
  DMA_K(0, 0); DMA_V(0, 0);
  asm volatile("s_waitcnt vmcnt(0)\n\ts_barrier" ::: "memory");
  DMA_K(1, 1); DMA_V(1, 1);
  BBODY(0);
  for (int kt = 1; kt < NKT; ++kt) {
    // counted wait: all-but-2 (the two nt-stores) complete -> DMA(kt)+bias done
    asm volatile("s_waitcnt vmcnt(2)\n\ts_barrier" ::: "memory");
    if (kt + 1 < NKT) {
      const int c2 = (kt + 1) & 1;
      DMA_K(c2, kt + 1); DMA_V(c2, kt + 1);
    }
    BBODY(kt);
  }

  #pragma unroll
  for (int dt = 0; dt < 8; ++dt) {
    #pragma unroll
    for (int r = 0; r < 4; ++r) {
      __builtin_nontemporal_store(oacc[dt][r],
          oA + (size_t)(row16 + (l4 << 2) + r) * DD + dt * 16 + l15);
    }
  }
}

extern "C" void kernel_launch(void* const* d_in, const int* in_sizes, int n_in,
                              void* d_out, int out_size, void* d_ws, size_t ws_size,
                              hipStream_t stream) {
  const float* q = (const float*)d_in[0];
  const float* k = (const float*)d_in[1];
  const float* v = (const float*)d_in[2];
  const int* mask = (const int*)d_in[3];
  const float* probs = (const float*)d_in[4];
  const float* alpha = (const float*)d_in[5];
  float* outA = (float*)d_out;
  float* outP = outA + (size_t)BB * HH * LL * DD;
  unsigned short* kbT = (unsigned short*)d_ws;
  unsigned short* vtT = kbT + (size_t)32 * 64 * 4096;
  unsigned short* biasW = vtT + (size_t)32 * 64 * 4096;
  float* invW = (float*)(biasW + (size_t)4096 * 2048);
  hipLaunchKernelGGL(prep_kernel, dim3(32 * 64), dim3(256), 0, stream,
                     k, v, mask, probs, alpha, kbT, vtT, biasW);
  hipLaunchKernelGGL(passA_kernel, dim3(BB * HH * (LL / QB)), dim3(256), 0, stream,
                     q, kbT, biasW, invW);
  hipLaunchKernelGGL(passB_kernel, dim3(BB * HH * (LL / QB)), dim3(256), 0, stream,
                     q, kbT, vtT, biasW, invW, outA, outP);
}

// Round 19
// 258.415 us; speedup vs baseline: 1.1136x; 1.1136x over previous
//
#include <hip/hip_runtime.h>

constexpr int BB = 2, HH = 16, LL = 2048, DD = 128;
constexpr int QB = 64, KB = 32, NKT = LL / KB;   // 64 k-tiles
constexpr float SCALE = 0.08838834764831845f;    // 1/sqrt(128)

typedef __attribute__((ext_vector_type(8))) short bf16x8;
typedef __attribute__((ext_vector_type(8))) unsigned short u16x8;
typedef __attribute__((ext_vector_type(4))) float f32x4;
typedef __attribute__((ext_vector_type(4))) int i32x4;

static __device__ __forceinline__ unsigned short f2bf(float f) {
  unsigned int u = __builtin_bit_cast(unsigned int, f);
  u += 0x7fffu + ((u >> 16) & 1u);   // RNE
  return (unsigned short)(u >> 16);
}
static __device__ __forceinline__ float bf2f(unsigned short h) {
  return __builtin_bit_cast(float, (unsigned int)h << 16);
}

#define GLD16(gsrc, ldst) __builtin_amdgcn_global_load_lds( \
    (const __attribute__((address_space(1))) void*)(gsrc), \
    (__attribute__((address_space(3))) void*)(ldst), 16, 0, 0)

// ---------------- prep ----------------
//   kbT tile [16 dslots][32 keys][8 d] (bf16)
//   vtT tile [4 kc][128 d][8 keys]     (bf16)
//   biasT[b][qt][kt][wid][lane][8]     (bf16) lane-packed: wave's per-iter bias
//     = ONE coalesced u16x8/lane; entry j<4 -> key l4*4+j, j>=4 -> 16+l4*4+j-4
__global__ __launch_bounds__(256)
void prep_kernel(const float* __restrict__ k, const float* __restrict__ v,
                 const int* __restrict__ mask, const float* __restrict__ probs,
                 const float* __restrict__ alphap,
                 unsigned short* __restrict__ kbT, unsigned short* __restrict__ vtT,
                 unsigned short* __restrict__ biasW)
{
  __shared__ unsigned short sT[128 * 40];   // V^T tile, 80 B rows
  const int bid = blockIdx.x;
  const int bh = bid >> 6, kt = bid & 63;
  const int t = threadIdx.x;
  const float alpha = alphap[0];
  const size_t tileBase = (size_t)bid * 4096;   // bid == bh*64 + kt
  const float* kg = k + ((size_t)bh * LL + kt * 32) * DD;
  const float* vg = v + ((size_t)bh * LL + kt * 32) * DD;

  // K -> 16B-block-transposed tile
  #pragma unroll
  for (int s = t; s < 512; s += 256) {
    int dsl = s >> 5, key = s & 31;
    const float* src = kg + key * DD + dsl * 8;
    float4 a = *(const float4*)src;
    float4 c = *(const float4*)(src + 4);
    u16x8 w;
    w[0] = f2bf(a.x); w[1] = f2bf(a.y); w[2] = f2bf(a.z); w[3] = f2bf(a.w);
    w[4] = f2bf(c.x); w[5] = f2bf(c.y); w[6] = f2bf(c.z); w[7] = f2bf(c.w);
    *(u16x8*)(kbT + tileBase + (size_t)s * 8) = w;
  }
  // V -> sT (transpose)
  #pragma unroll
  for (int i = 0; i < 4; ++i) {
    int idx = i * 256 + t;
    int key = idx >> 5, d4 = (idx & 31) * 4;
    float4 x = ((const float4*)vg)[idx];
    sT[(d4 + 0) * 40 + key] = f2bf(x.x);
    sT[(d4 + 1) * 40 + key] = f2bf(x.y);
    sT[(d4 + 2) * 40 + key] = f2bf(x.z);
    sT[(d4 + 3) * 40 + key] = f2bf(x.w);
  }
  // biasT: 2 tiles per block (4096 tiles total, 2048 u16 each)
  #pragma unroll
  for (int it = 0; it < 2; ++it) {
    int tileIdx = bid * 2 + it;            // 0..4095
    int b = tileIdx >> 11;
    int rem = tileIdx & 2047;
    int tq = rem >> 6;                     // qt 0..31
    int tk = rem & 63;                     // kt 0..63
    int row = ((t >> 6) << 4) + (t & 15);  // widx*16 + l15
    int kc = ((t >> 4) & 3) * 4;           // l4*4
    const float* pr = probs + (size_t)b * LL * LL + (size_t)(tq * 64 + row) * LL + tk * 32;
    const int* mr = mask + (size_t)b * LL * LL + (size_t)(tq * 64 + row) * LL + tk * 32;
    float4 f0 = *(const float4*)(pr + kc);
    float4 f1 = *(const float4*)(pr + kc + 16);
    int4 m0 = *(const int4*)(mr + kc);
    int4 m1 = *(const int4*)(mr + kc + 16);
    u16x8 o;
    o[0] = f2bf(m0.x ? f0.x * alpha : -1e30f);
    o[1] = f2bf(m0.y ? f0.y * alpha : -1e30f);
    o[2] = f2bf(m0.z ? f0.z * alpha : -1e30f);
    o[3] = f2bf(m0.w ? f0.w * alpha : -1e30f);
    o[4] = f2bf(m1.x ? f1.x * alpha : -1e30f);
    o[5] = f2bf(m1.y ? f1.y * alpha : -1e30f);
    o[6] = f2bf(m1.z ? f1.z * alpha : -1e30f);
    o[7] = f2bf(m1.w ? f1.w * alpha : -1e30f);
    *(u16x8*)(biasW + (size_t)tileIdx * 2048 + t * 8) = o;
  }
  __syncthreads();
  // sT -> vtT tile [kc][d][8]
  #pragma unroll
  for (int s = t; s < 512; s += 256) {
    int kc = s >> 7, d = s & 127;
    u16x8 w = *(const u16x8*)&sT[d * 40 + kc * 8];
    *(u16x8*)(vtT + tileBase + (size_t)s * 8) = w;
  }
}

// ---------------- pass A: rowsums -> invW ----------------
__global__ __launch_bounds__(256, 6)
void passA_kernel(const float* __restrict__ q, const unsigned short* __restrict__ kbT,
                  const unsigned short* __restrict__ biasW, float* __restrict__ invW)
{
  __shared__ unsigned short sK[2][4096];

  const int tid = threadIdx.x;
  const int lane = tid & 63;
  const int wid = tid >> 6;
  const int l15 = lane & 15;
  const int l4 = lane >> 4;

  const int bid = blockIdx.x;
  const int work = ((bid & 7) << 7) | (bid >> 3);
  const int bh = work >> 5;
  const int qt = work & 31;
  const int b = bh >> 4;
  const int q0 = qt * QB;
  const int row16 = wid << 4;

  const unsigned short* kbh = kbT + (size_t)bh * 64 * 4096;
  const unsigned short* bg = biasW + ((size_t)(b * 32 + qt) * 64) * 2048 + (wid << 9) + (lane << 3);

  bf16x8 qf0, qf1, qf2, qf3;
  {
    const float* qs = q + (size_t)(bh * LL + q0 + row16 + l15) * DD + l4 * 8;
    #define LQ(FR, KC) { \
      float4 a = *(const float4*)(qs + (KC) * 32); \
      float4 c = *(const float4*)(qs + (KC) * 32 + 4); \
      FR[0]=(short)f2bf(a.x); FR[1]=(short)f2bf(a.y); FR[2]=(short)f2bf(a.z); FR[3]=(short)f2bf(a.w); \
      FR[4]=(short)f2bf(c.x); FR[5]=(short)f2bf(c.y); FR[6]=(short)f2bf(c.z); FR[7]=(short)f2bf(c.w); }
    LQ(qf0, 0) LQ(qf1, 1) LQ(qf2, 2) LQ(qf3, 3)
    #undef LQ
  }

  #define DMA_K(BUF, KT) do { \
    GLD16(kbh + (size_t)(KT) * 4096 + tid * 8,         &sK[BUF][wid << 9]); \
    GLD16(kbh + (size_t)(KT) * 4096 + (256 + tid) * 8, &sK[BUF][2048 + (wid << 9)]); } while (0)

  #define QKS(KC, QF) { \
    bf16x8 k0 = *(const bf16x8*)&sK[cur][(((KC) * 4 + l4) * 32 + l15) * 8]; \
    a0 = __builtin_amdgcn_mfma_f32_16x16x32_bf16(k0, QF, a0, 0, 0, 0); \
    bf16x8 k1 = *(const bf16x8*)&sK[cur][(((KC) * 4 + l4) * 32 + 16 + l15) * 8]; \
    a1 = __builtin_amdgcn_mfma_f32_16x16x32_bf16(k1, QF, a1, 0, 0, 0); }

  DMA_K(0, 0);
  u16x8 cnb = *(const u16x8*)(bg);
  float sum = 0.f;
  for (int kt = 0; kt < NKT; ++kt) {
    const int cur = kt & 1;
    __syncthreads();
    if (kt + 1 < NKT) DMA_K(cur ^ 1, kt + 1);
    u16x8 bt = cnb;
    if (kt + 1 < NKT) cnb = *(const u16x8*)(bg + (size_t)(kt + 1) * 2048);
    f32x4 a0 = {0.f,0.f,0.f,0.f}, a1 = {0.f,0.f,0.f,0.f};
    QKS(0, qf0) QKS(1, qf1) QKS(2, qf2) QKS(3, qf3)
    sum += __expf(a0[0] * SCALE + bf2f(bt[0]));
    sum += __expf(a0[1] * SCALE + bf2f(bt[1]));
    sum += __expf(a0[2] * SCALE + bf2f(bt[2]));
    sum += __expf(a0[3] * SCALE + bf2f(bt[3]));
    sum += __expf(a1[0] * SCALE + bf2f(bt[4]));
    sum += __expf(a1[1] * SCALE + bf2f(bt[5]));
    sum += __expf(a1[2] * SCALE + bf2f(bt[6]));
    sum += __expf(a1[3] * SCALE + bf2f(bt[7]));
  }
  sum += __shfl_xor(sum, 16, 64);
  sum += __shfl_xor(sum, 32, 64);
  if (l4 == 0)
    invW[(size_t)bh * LL + q0 + row16 + l15] = 1.0f / sum;
  #undef DMA_K
  #undef QKS
}

// ---------------- pass B: attn_p + O ----------------
__global__ __launch_bounds__(256, 4)
void passB_kernel(const float* __restrict__ q, const unsigned short* __restrict__ kbT,
                  const unsigned short* __restrict__ vtT, const unsigned short* __restrict__ biasW,
                  const float* __restrict__ invW,
                  float* __restrict__ outA, float* __restrict__ outP)
{
  __shared__ unsigned short sK[2][4096];
  __shared__ unsigned short sVt[2][4096];

  const int tid = threadIdx.x;
  const int lane = tid & 63;
  const int wid = tid >> 6;
  const int l15 = lane & 15;
  const int l4 = lane >> 4;

  const int bid = blockIdx.x;
  const int work = ((bid & 7) << 7) | (bid >> 3);
  const int bh = work >> 5;
  const int qt = work & 31;
  const int b = bh >> 4;
  const int q0 = qt * QB;
  const int row16 = wid << 4;

  const unsigned short* kbh = kbT + (size_t)bh * 64 * 4096;
  const unsigned short* vbh = vtT + (size_t)bh * 64 * 4096;
  const unsigned short* bg = biasW + ((size_t)(b * 32 + qt) * 64) * 2048 + (wid << 9) + (lane << 3);
  float* oA = outA + (size_t)(bh * LL + q0) * DD;
  float* oPr = outP + (size_t)bh * LL * LL + (size_t)(q0 + row16 + l15) * LL;

  const float inv = invW[(size_t)bh * LL + q0 + row16 + l15];

  bf16x8 qf0, qf1, qf2, qf3;
  {
    const float* qs = q + (size_t)(bh * LL + q0 + row16 + l15) * DD + l4 * 8;
    #define LQ(FR, KC) { \
      float4 a = *(const float4*)(qs + (KC) * 32); \
      float4 c = *(const float4*)(qs + (KC) * 32 + 4); \
      FR[0]=(short)f2bf(a.x); FR[1]=(short)f2bf(a.y); FR[2]=(short)f2bf(a.z); FR[3]=(short)f2bf(a.w); \
      FR[4]=(short)f2bf(c.x); FR[5]=(short)f2bf(c.y); FR[6]=(short)f2bf(c.z); FR[7]=(short)f2bf(c.w); }
    LQ(qf0, 0) LQ(qf1, 1) LQ(qf2, 2) LQ(qf3, 3)
    #undef LQ
  }

  #define DMA_K(BUF, KT) do { \
    GLD16(kbh + (size_t)(KT) * 4096 + tid * 8,         &sK[BUF][wid << 9]); \
    GLD16(kbh + (size_t)(KT) * 4096 + (256 + tid) * 8, &sK[BUF][2048 + (wid << 9)]); } while (0)
  #define DMA_V(BUF, KT) do { \
    GLD16(vbh + (size_t)(KT) * 4096 + tid * 8,         &sVt[BUF][wid << 9]); \
    GLD16(vbh + (size_t)(KT) * 4096 + (256 + tid) * 8, &sVt[BUF][2048 + (wid << 9)]); } while (0)

  #define QKS(KC, QF) { \
    bf16x8 k0 = *(const bf16x8*)&sK[cur][(((KC) * 4 + l4) * 32 + l15) * 8]; \
    a0 = __builtin_amdgcn_mfma_f32_16x16x32_bf16(k0, QF, a0, 0, 0, 0); \
    bf16x8 k1 = *(const bf16x8*)&sK[cur][(((KC) * 4 + l4) * 32 + 16 + l15) * 8]; \
    a1 = __builtin_amdgcn_mfma_f32_16x16x32_bf16(k1, QF, a1, 0, 0, 0); }

  const int srcA = l15 + (((l4 << 1) + 0) & 3) * 16;
  const int srcB = l15 + (((l4 << 1) + 1) & 3) * 16;
  const bool hiTile = (l4 >= 2);

  f32x4 oacc[8];
  #pragma unroll
  for (int dt = 0; dt < 8; ++dt) oacc[dt] = (f32x4){0.f,0.f,0.f,0.f};

  u16x8 cnb;

  // body macro: compute iteration KT from buf cur; prefetches handled by caller
  #define BBODY(KT) do { \
    const int cur = (KT) & 1; \
    u16x8 bt = cnb; \
    if ((KT) + 1 < NKT) cnb = *(const u16x8*)(bg + (size_t)((KT) + 1) * 2048); \
    f32x4 a0 = {0.f,0.f,0.f,0.f}, a1 = {0.f,0.f,0.f,0.f}; \
    QKS(0, qf0) QKS(1, qf1) QKS(2, qf2) QKS(3, qf3) \
    f32x4 p0, p1; \
    p0[0] = __expf(a0[0] * SCALE + bf2f(bt[0])) * inv; \
    p0[1] = __expf(a0[1] * SCALE + bf2f(bt[1])) * inv; \
    p0[2] = __expf(a0[2] * SCALE + bf2f(bt[2])) * inv; \
    p0[3] = __expf(a0[3] * SCALE + bf2f(bt[3])) * inv; \
    p1[0] = __expf(a1[0] * SCALE + bf2f(bt[4])) * inv; \
    p1[1] = __expf(a1[1] * SCALE + bf2f(bt[5])) * inv; \
    p1[2] = __expf(a1[2] * SCALE + bf2f(bt[6])) * inv; \
    p1[3] = __expf(a1[3] * SCALE + bf2f(bt[7])) * inv; \
    __builtin_nontemporal_store(p0, (f32x4*)(oPr + (KT) * 32 + (l4 << 2))); \
    __builtin_nontemporal_store(p1, (f32x4*)(oPr + (KT) * 32 + 16 + (l4 << 2))); \
    unsigned d00, d01, d10, d11; \
    asm("v_cvt_pk_bf16_f32 %0, %1, %2" : "=v"(d00) : "v"(p0[0]), "v"(p0[1])); \
    asm("v_cvt_pk_bf16_f32 %0, %1, %2" : "=v"(d01) : "v"(p0[2]), "v"(p0[3])); \
    asm("v_cvt_pk_bf16_f32 %0, %1, %2" : "=v"(d10) : "v"(p1[0]), "v"(p1[1])); \
    asm("v_cvt_pk_bf16_f32 %0, %1, %2" : "=v"(d11) : "v"(p1[2]), "v"(p1[3])); \
    int a00 = __shfl((int)d00, srcA, 64); \
    int a01 = __shfl((int)d01, srcA, 64); \
    int a02 = __shfl((int)d00, srcB, 64); \
    int a03 = __shfl((int)d01, srcB, 64); \
    int b00 = __shfl((int)d10, srcA, 64); \
    int b01 = __shfl((int)d11, srcA, 64); \
    int b02 = __shfl((int)d10, srcB, 64); \
    int b03 = __shfl((int)d11, srcB, 64); \
    i32x4 fw; \
    fw[0] = hiTile ? b00 : a00; \
    fw[1] = hiTile ? b01 : a01; \
    fw[2] = hiTile ? b02 : a02; \
    fw[3] = hiTile ? b03 : a03; \
    bf16x8 aP = __builtin_bit_cast(bf16x8, fw); \
    _Pragma("unroll") \
    for (int dt = 0; dt < 8; ++dt) { \
      bf16x8 bV = *(const bf16x8*)&sVt[cur][(l4 * 128 + dt * 16 + l15) * 8]; \
      oacc[dt] = __builtin_amdgcn_mfma_f32_16x16x32_bf16(aP, bV, oacc[dt], 0, 0, 0); \
    } \
  } while (0)

  // prologue: bias first, then DMA (stores later stay the newest-2 ops)
  cnb = *(const u16x8*)(bg);
  DMA_K(0, 0); DMA_V(0, 0);
  asm volatile("s_waitcnt vmcnt(0)\n\ts_barrier" ::: "memory");
  // iter 0 (no stores outstanding yet, but uniform handling after this)
  DMA_K(1, 1); DMA_V(1, 1);
  BBODY(0);
  for (int kt = 1; kt < NKT; ++kt) {
    // counted wait: all-but-2 (the two nt-stores) complete -> DMA(kt)+bias done,
    // stores keep draining in background
    asm volatile("s_waitcnt vmcnt(2)\n\ts_barrier" ::: "memory");
    if (kt + 1 < NKT) {
      const int c2 = (kt + 1) & 1;
      DMA_K(c2, kt + 1); DMA_V(c2, kt + 1);
    }
    BBODY(kt);
  }

  #pragma unroll
  for (int dt = 0; dt < 8; ++dt) {
    #pragma unroll
    for (int r = 0; r < 4; ++r) {
      __builtin_nontemporal_store(oacc[dt][r],
          oA + (size_t)(row16 + (l4 << 2) + r) * DD + dt * 16 + l15);
    }
  }
}

extern "C" void kernel_launch(void* const* d_in, const int* in_sizes, int n_in,
                              void* d_out, int out_size, void* d_ws, size_t ws_size,
                              hipStream_t stream) {
  const float* q = (const float*)d_in[0];
  const float* k = (const float*)d_in[1];
  const float* v = (const float*)d_in[2];
  const int* mask = (const int*)d_in[3];
  const float* probs = (const float*)d_in[4];
  const float* alpha = (const float*)d_in[5];
  float* outA = (float*)d_out;
  float* outP = outA + (size_t)BB * HH * LL * DD;
  unsigned short* kbT = (unsigned short*)d_ws;
  unsigned short* vtT = kbT + (size_t)32 * 64 * 4096;
  unsigned short* biasW = vtT + (size_t)32 * 64 * 4096;
  float* invW = (float*)(biasW + (size_t)4096 * 2048);
  hipLaunchKernelGGL(prep_kernel, dim3(32 * 64), dim3(256), 0, stream,
                     k, v, mask, probs, alpha, kbT, vtT, biasW);
  hipLaunchKernelGGL(passA_kernel, dim3(BB * HH * (LL / QB)), dim3(256), 0, stream,
                     q, kbT, biasW, invW);
  hipLaunchKernelGGL(passB_kernel, dim3(BB * HH * (LL / QB)), dim3(256), 0, stream,
                     q, kbT, vtT, biasW, invW, outA, outP);
}